// Round 1
// baseline (3252.144 us; speedup 1.0000x reference)
//
#include <hip/hip_runtime.h>
#include <hip/hip_bf16.h>
#include <cstdint>
#include <cstddef>

// Problem dims
#define SS   512
#define BB   64
#define EMBD 512
#define HIDD 512
#define MAXD 1024
#define NCLS 20
#define KCAT 1536
#define ROWS (SS*BB)   // 32768

// ---------- small helpers ----------
__device__ __forceinline__ uint16_t f2bf(float f) {
  uint32_t u = __float_as_uint(f);
  uint32_t r = u + 0x7fffu + ((u >> 16) & 1u);
  return (uint16_t)(r >> 16);
}
__device__ __forceinline__ float bf2f(uint32_t h) {
  return __uint_as_float(h << 16);
}
__device__ __forceinline__ uint32_t pk2(float a, float b) {
  return (uint32_t)f2bf(a) | ((uint32_t)f2bf(b) << 16);
}

// bf16 pair dot product: acc += w.x*c.x + w.y*c.y
#if defined(__has_builtin)
#if __has_builtin(__builtin_amdgcn_fdot2_f32_bf16)
#define USE_BF16_DOT2 1
#endif
#endif

#ifdef USE_BF16_DOT2
typedef __bf16 bf16x2_t __attribute__((ext_vector_type(2)));
__device__ __forceinline__ float dot2bf(uint32_t w, uint32_t c, float acc) {
  return __builtin_amdgcn_fdot2_f32_bf16(__builtin_bit_cast(bf16x2_t, w),
                                         __builtin_bit_cast(bf16x2_t, c), acc, false);
}
#else
__device__ __forceinline__ float dot2bf(uint32_t w, uint32_t c, float acc) {
  float w0 = __uint_as_float(w << 16);
  float w1 = __uint_as_float(w & 0xffff0000u);
  float c0 = __uint_as_float(c << 16);
  float c1 = __uint_as_float(c & 0xffff0000u);
  return fmaf(w1, c1, fmaf(w0, c0, acc));
}
#endif

__device__ __forceinline__ void gl_lds16(const void* g, void* l) {
  __builtin_amdgcn_global_load_lds((const __attribute__((address_space(1))) void*)g,
                                   (__attribute__((address_space(3))) void*)l,
                                   16, 0, 0);
}

typedef short v8s __attribute__((ext_vector_type(8)));
typedef float v4f __attribute__((ext_vector_type(4)));

// ---------- K0: gather emb -> cat[:,512:1024] (bf16), convert weights to bf16 ----------
__global__ __launch_bounds__(256) void prep_kernel(
    const int* __restrict__ inp, const float* __restrict__ table,
    const float* __restrict__ Wsl, const float* __restrict__ Wsr,
    const float* __restrict__ Wmax,
    uint16_t* __restrict__ cat, uint16_t* __restrict__ wslb,
    uint16_t* __restrict__ wsrb, uint16_t* __restrict__ wmaxb)
{
  const int blk = blockIdx.x, t = threadIdx.x;
  if (blk < 8192) {
    const int r = blk * 4 + (t >> 6);
    const int lane = t & 63;
    const int token = inp[r];
    const float4* src = (const float4*)(table + (size_t)token * EMBD);
    uint16_t* dst = cat + (size_t)r * KCAT + 512;
#pragma unroll
    for (int p = 0; p < 2; ++p) {
      const int slot = lane + 64 * p;   // 0..127 float4 slots per row
      float4 v = src[slot];
      uint2 o;
      o.x = pk2(v.x, v.y);
      o.y = pk2(v.z, v.w);
      *(uint2*)(dst + slot * 4) = o;
    }
  } else {
    size_t flat = (size_t)(blk - 8192) * 2048 + (size_t)t * 8;
    const float* src; uint16_t* dst; size_t off;
    if (flat < 262144)      { src = Wsl;  dst = wslb;  off = flat; }
    else if (flat < 524288) { src = Wsr;  dst = wsrb;  off = flat - 262144; }
    else                    { src = Wmax; dst = wmaxb; off = flat - 524288; }
    float4 v0 = *(const float4*)(src + off);
    float4 v1 = *(const float4*)(src + off + 4);
    uint4 o;
    o.x = pk2(v0.x, v0.y); o.y = pk2(v0.z, v0.w);
    o.z = pk2(v1.x, v1.y); o.w = pk2(v1.z, v1.w);
    *(uint4*)(dst + off) = o;
  }
}

// ---------- GEMM (m97-style): C[M x 1024] = A[M x K] @ W^T, 128x128 tiles, BK=64 ----------
// MODE 0: out = A@W^T + bias -> bf16 store (proj GEMM, W split at n=512)
// MODE 1: v = tanh(A@W^T + bias); partial[mb][b][n] = max over the block's 2 s-rows
template<int MODE>
__global__ __launch_bounds__(256, 2) void gemm_kernel(
    const uint16_t* __restrict__ A, int lda, int K,
    const uint16_t* __restrict__ W0, const uint16_t* __restrict__ W1,
    const float* __restrict__ bias0, const float* __restrict__ bias1,
    uint16_t* __restrict__ outb, float* __restrict__ partial)
{
  __shared__ unsigned char smem[32768];
  uint16_t* lA = (uint16_t*)smem;            // 128x64 bf16 = 16 KB
  uint16_t* lW = (uint16_t*)(smem + 16384);  // 128x64 bf16 = 16 KB

  const int tid = threadIdx.x;
  const int mb = blockIdx.x, nb = blockIdx.y;
  const int m0 = mb * 128, n0 = nb * 128;

  const uint16_t* Wp = W0;
  const float* biasp = bias0;
  int nr0 = n0;
  if (MODE == 0 && n0 >= 512) { Wp = W1; biasp = bias1; nr0 = n0 - 512; }

  const int w = tid >> 6, lane = tid & 63;
  const int mw = w & 1, nw = w >> 1;

  v4f acc[4][4];
#pragma unroll
  for (int i = 0; i < 4; ++i)
#pragma unroll
    for (int j = 0; j < 4; ++j) {
      v4f z = {0.f, 0.f, 0.f, 0.f};
      acc[i][j] = z;
    }

  const int r_st = tid >> 3;   // + p*32
  const int u_st = tid & 7;

  for (int kk = 0; kk < K; kk += 64) {
    __syncthreads();
#pragma unroll
    for (int p = 0; p < 4; ++p) {
      const int r = p * 32 + r_st;
      gl_lds16(A + (size_t)(m0 + r) * lda + kk + u_st * 8, lA + (p * 256 + tid) * 8);
    }
#pragma unroll
    for (int p = 0; p < 4; ++p) {
      const int r = p * 32 + r_st;
      gl_lds16(Wp + (size_t)(nr0 + r) * K + kk + u_st * 8, lW + (p * 256 + tid) * 8);
    }
    __syncthreads();
#pragma unroll
    for (int ks = 0; ks < 2; ++ks) {
      v8s af[4], wf[4];
#pragma unroll
      for (int i = 0; i < 4; ++i)
        af[i] = *(const v8s*)&lA[(mw * 64 + i * 16 + (lane & 15)) * 64 + ks * 32 + (lane >> 4) * 8];
#pragma unroll
      for (int j = 0; j < 4; ++j)
        wf[j] = *(const v8s*)&lW[(nw * 64 + j * 16 + (lane & 15)) * 64 + ks * 32 + (lane >> 4) * 8];
#pragma unroll
      for (int i = 0; i < 4; ++i)
#pragma unroll
        for (int j = 0; j < 4; ++j)
          acc[i][j] = __builtin_amdgcn_mfma_f32_16x16x32_bf16(af[i], wf[j], acc[i][j], 0, 0, 0);
    }
  }

  __syncthreads();  // all LDS frag reads done before epilogue reuse

  if (MODE == 0) {
#pragma unroll
    for (int i = 0; i < 4; ++i)
#pragma unroll
      for (int j = 0; j < 4; ++j) {
        const int nl = nw * 64 + j * 16 + (lane & 15);
        const float bv = biasp[nr0 + nl];
        const int colg = n0 + nl;
#pragma unroll
        for (int r = 0; r < 4; ++r) {
          const int rowg = m0 + mw * 64 + i * 16 + (lane >> 4) * 4 + r;
          outb[(size_t)rowg * 1024 + colg] = f2bf(acc[i][j][r] + bv);
        }
      }
  } else {
    float* lred = (float*)smem;   // 64 b x 128 n f32 = 32 KB
    if (mw == 1) {
#pragma unroll
      for (int i = 0; i < 4; ++i)
#pragma unroll
        for (int j = 0; j < 4; ++j) {
          const int nl = nw * 64 + j * 16 + (lane & 15);
          const float bv = biasp[nr0 + nl];
#pragma unroll
          for (int r = 0; r < 4; ++r) {
            const int bl = i * 16 + (lane >> 4) * 4 + r;
            lred[bl * 128 + nl] = tanhf(acc[i][j][r] + bv);
          }
        }
    }
    __syncthreads();
    if (mw == 0) {
#pragma unroll
      for (int i = 0; i < 4; ++i)
#pragma unroll
        for (int j = 0; j < 4; ++j) {
          const int nl = nw * 64 + j * 16 + (lane & 15);
          const float bv = biasp[nr0 + nl];
#pragma unroll
          for (int r = 0; r < 4; ++r) {
            const int bl = i * 16 + (lane >> 4) * 4 + r;
            const float v = tanhf(acc[i][j][r] + bv);
            partial[((size_t)mb * 64 + bl) * 1024 + n0 + nl] = fmaxf(v, lred[bl * 128 + nl]);
          }
        }
    }
  }
}

// ---------- K2: bidirectional recurrence ----------
// 256 blocks: (batch b, dir d, half hf). W chunk (256 h x 512 k) held in VGPRs (bf16 pairs).
// Pairwise exchange of c-halves via agent-scope atomics, parity-double-buffered.
__global__ __launch_bounds__(512, 2) void scan_kernel(
    const uint16_t* __restrict__ ee,     // [32768][1024] bf16: ls | rs
    const float* __restrict__ Wl, const float* __restrict__ Wr,
    const float* __restrict__ bl, const float* __restrict__ br,
    const float* __restrict__ cl0, const float* __restrict__ cr0,
    uint16_t* __restrict__ cat,
    uint32_t* __restrict__ cbuf, uint32_t* __restrict__ flags)
{
  const int tid = threadIdx.x;
  const int bid = blockIdx.x;
  const int x = bid & 7, g = bid >> 3;
  const int hf = g & 1;
  const int id = x * 16 + (g >> 1);   // 0..127 == (b,d)
  const int b = id >> 1, d = id & 1;
  const int pbid = bid ^ 8;           // partner: same XCD under i%8 round-robin

  const int w = tid >> 6, lane = tid & 63;
  const int rloc = (w & 3) * 64 + lane;  // 0..255  (row within half)
  const int kq = w >> 2;                 // 0/1: k window 256
  const int h = hf * 256 + rloc;

  // load + pack W chunk into registers
  const float* Wmat = d ? Wr : Wl;
  const float* wrow = Wmat + (size_t)h * HIDD + kq * 256;
  uint32_t wreg[128];
#pragma unroll
  for (int jj = 0; jj < 64; ++jj) {
    float4 q = ((const float4*)wrow)[jj];
    wreg[2 * jj]     = pk2(q.x, q.y);
    wreg[2 * jj + 1] = pk2(q.z, q.w);
  }

  __shared__ uint32_t cpair[256];   // full c (512 bf16) as pairs
  __shared__ float2 part2[256];     // per-row partial sums (kq0,kq1)

  // init c = c0 (full vector, locally known)
  const float* c0v = d ? cr0 : cl0;
  if (tid < 256) {
    float2 cv = ((const float2*)c0v)[tid];
    cpair[tid] = pk2(cv.x, cv.y);
  }
  float2 biasv = {0.f, 0.f};
  if (tid < 128) {
    const float* bvec = (d ? br : bl) + hf * 256;
    biasv = ((const float2*)bvec)[tid];
  }
  __syncthreads();

  for (int i = 0; i < 512; ++i) {
    const int s = d ? (511 - i) : i;
    uint32_t epair = 0;
    if (tid < 128)
      epair = *(const uint32_t*)&ee[(size_t)(s * BB + b) * 1024 + d * 512 + hf * 256 + 2 * tid];

    // dot: rows rloc, k window [kq*256, +256)
    const uint32_t* cb = &cpair[kq * 128];
    float a0 = 0.f, a1 = 0.f, a2 = 0.f, a3 = 0.f;
#pragma unroll
    for (int jj = 0; jj < 32; ++jj) {
      uint4 cc = *(const uint4*)(cb + 4 * jj);
      a0 = dot2bf(wreg[4 * jj + 0], cc.x, a0);
      a1 = dot2bf(wreg[4 * jj + 1], cc.y, a1);
      a2 = dot2bf(wreg[4 * jj + 2], cc.z, a2);
      a3 = dot2bf(wreg[4 * jj + 3], cc.w, a3);
    }
    ((float*)&part2[rloc])[kq] = (a0 + a1) + (a2 + a3);
    __syncthreads();

    // finalize rows 2t, 2t+1; publish own half
    if (tid < 128) {
      float4 p4 = *(const float4*)&part2[2 * tid];
      float s0 = p4.x + p4.y + biasv.x + bf2f(epair & 0xffffu);
      float s1 = p4.z + p4.w + biasv.y + bf2f(epair >> 16);
      float c0n = tanhf(s0), c1n = tanhf(s1);
      uint32_t pr = (uint32_t)f2bf(c0n) | ((uint32_t)f2bf(c1n) << 16);
      const int col = (d ? 1024 : 0) + hf * 256 + 2 * tid;
      *(uint32_t*)&cat[(size_t)(s * BB + b) * KCAT + col] = pr;
      cpair[hf * 128 + tid] = pr;
      if (i != 511) {
        uint32_t* slot = cbuf + ((((i & 1) * 128 + id) * 2 + hf) * 128) + tid;
        __hip_atomic_store(slot, pr, __ATOMIC_RELAXED, __HIP_MEMORY_SCOPE_AGENT);
      }
    }
    if (i == 511) break;

    __syncthreads();   // drains vmem: published data complete before flag
    if (tid == 0) {
      __hip_atomic_store(&flags[bid], (uint32_t)(i + 1), __ATOMIC_RELEASE, __HIP_MEMORY_SCOPE_AGENT);
      while (__hip_atomic_load(&flags[pbid], __ATOMIC_ACQUIRE, __HIP_MEMORY_SCOPE_AGENT) < (uint32_t)(i + 1)) {
        __builtin_amdgcn_s_sleep(2);
      }
    }
    __syncthreads();
    if (tid < 128) {
      const uint32_t* pslot = cbuf + ((((i & 1) * 128 + id) * 2 + (hf ^ 1)) * 128) + tid;
      uint32_t pv = __hip_atomic_load(pslot, __ATOMIC_RELAXED, __HIP_MEMORY_SCOPE_AGENT);
      cpair[(hf ^ 1) * 128 + tid] = pv;
    }
    __syncthreads();
  }
}

// ---------- K4: max-reduce partials, classifier, log_softmax ----------
__global__ __launch_bounds__(256) void final_kernel(
    const float* __restrict__ partial, const float* __restrict__ Wdoc,
    const float* __restrict__ bdoc, float* __restrict__ out)
{
  const int b = blockIdx.x, t = threadIdx.x;
  __shared__ float ym[1024];
  __shared__ float lg[32];
  float m0 = -2.f, m1 = -2.f, m2 = -2.f, m3 = -2.f;
  for (int mg = 0; mg < 256; ++mg) {
    const float* p = partial + ((size_t)mg * 64 + b) * 1024;
    m0 = fmaxf(m0, p[t]);
    m1 = fmaxf(m1, p[t + 256]);
    m2 = fmaxf(m2, p[t + 512]);
    m3 = fmaxf(m3, p[t + 768]);
  }
  ym[t] = m0; ym[t + 256] = m1; ym[t + 512] = m2; ym[t + 768] = m3;
  __syncthreads();
  if (t < NCLS) {
    const float* wr = Wdoc + (size_t)t * 1024;
    float a0 = 0.f, a1 = 0.f, a2 = 0.f, a3 = 0.f;
    for (int n = 0; n < 1024; n += 4) {
      a0 = fmaf(ym[n], wr[n], a0);
      a1 = fmaf(ym[n + 1], wr[n + 1], a1);
      a2 = fmaf(ym[n + 2], wr[n + 2], a2);
      a3 = fmaf(ym[n + 3], wr[n + 3], a3);
    }
    lg[t] = (a0 + a1) + (a2 + a3) + bdoc[t];
  }
  __syncthreads();
  if (t < NCLS) {
    float mx = -1e30f;
    for (int c = 0; c < NCLS; ++c) mx = fmaxf(mx, lg[c]);
    float ssum = 0.f;
    for (int c = 0; c < NCLS; ++c) ssum += expf(lg[c] - mx);
    out[b * NCLS + t] = lg[t] - mx - logf(ssum);
  }
}

// ---------- launch ----------
extern "C" void kernel_launch(void* const* d_in, const int* in_sizes, int n_in,
                              void* d_out, int out_size, void* d_ws, size_t ws_size,
                              hipStream_t stream) {
  const int*   inp   = (const int*)  d_in[0];
  const float* table = (const float*)d_in[1];
  const float* cl0   = (const float*)d_in[2];
  const float* cr0   = (const float*)d_in[3];
  const float* Wl    = (const float*)d_in[4];
  const float* bl    = (const float*)d_in[5];
  const float* Wr    = (const float*)d_in[6];
  const float* br    = (const float*)d_in[7];
  const float* Wsl   = (const float*)d_in[8];
  const float* bsl   = (const float*)d_in[9];
  const float* Wsr   = (const float*)d_in[10];
  const float* bsr   = (const float*)d_in[11];
  const float* Wmax  = (const float*)d_in[12];
  const float* bmax  = (const float*)d_in[13];
  const float* Wdoc  = (const float*)d_in[14];
  const float* bdoc  = (const float*)d_in[15];

  uint8_t* ws = (uint8_t*)d_ws;
  uint16_t* cat     = (uint16_t*)(ws);                 // 32768*1536*2 = 100663296
  uint16_t* ee      = (uint16_t*)(ws + 100663296);     // 32768*1024*2 = 67108864
  float*    partial = (float*)   (ws + 167772160);     // 256*64*1024*4 = 67108864
  uint16_t* wslb    = (uint16_t*)(ws + 234881024);     // 524288
  uint16_t* wsrb    = (uint16_t*)(ws + 235405312);     // 524288
  uint16_t* wmaxb   = (uint16_t*)(ws + 235929600);     // 3145728
  uint32_t* cbuf    = (uint32_t*)(ws + 239075328);     // 262144
  uint32_t* flags   = (uint32_t*)(ws + 239337472);     // 1024

  hipMemsetAsync(flags, 0, 1024, stream);
  prep_kernel<<<9216, 256, 0, stream>>>(inp, table, Wsl, Wsr, Wmax, cat, wslb, wsrb, wmaxb);
  gemm_kernel<0><<<dim3(256, 8), 256, 0, stream>>>(cat + 512, KCAT, 512, wslb, wsrb,
                                                   bsl, bsr, ee, nullptr);
  scan_kernel<<<256, 512, 0, stream>>>(ee, Wl, Wr, bl, br, cl0, cr0, cat, cbuf, flags);
  gemm_kernel<1><<<dim3(256, 8), 256, 0, stream>>>(cat, KCAT, KCAT, wmaxb, nullptr,
                                                   bmax, nullptr, nullptr, partial);
  final_kernel<<<64, 256, 0, stream>>>(partial, Wdoc, bdoc, (float*)d_out);
}